// Round 1
// baseline (339.925 us; speedup 1.0000x reference)
//
#include <hip/hip_runtime.h>

// ---------------------------------------------------------------------------
// VectorQuantizer: inputs [32,32,32,256] f32, embeddings [256,1024] f32.
// Out: quantized [32,32,32,256] f32 (= gathered nearest codebook column),
//      loss scalar = 1.25 * mean((q - x)^2).
// Score for argmin: s_k = |e_k|^2 - 2 * x.e_k   (|x|^2 dropped: row-constant)
// ---------------------------------------------------------------------------

constexpr int Mrows = 32768;   // 32*32*32
constexpr int Ddim  = 256;
constexpr int Kcode = 1024;

constexpr int BM = 128, BN = 128, BK = 32;
constexpr int TM = 8,  TN = 8;   // 16x16 threads, 8x8 microtile

// ---- codebook transpose: E [D][K] -> ET [K][D] (coalesced gather later) ----
__global__ __launch_bounds__(256)
void vq_prep_transpose(const float* __restrict__ E, float* __restrict__ ET) {
    __shared__ float t[32][33];
    const int k0 = (blockIdx.x % 32) * 32;
    const int d0 = (blockIdx.x / 32) * 32;
    const int tx = threadIdx.x % 32;   // k (load) / d (store)
    const int ty = threadIdx.x / 32;   // 8 rows per pass
    #pragma unroll
    for (int i = 0; i < 32; i += 8)
        t[ty + i][tx] = E[(size_t)(d0 + ty + i) * Kcode + k0 + tx];
    __syncthreads();
    #pragma unroll
    for (int i = 0; i < 32; i += 8)
        ET[(size_t)(k0 + ty + i) * Ddim + d0 + tx] = t[tx][ty + i];
}

// ---- per-code squared norms ----
__global__ __launch_bounds__(256)
void vq_norms(const float* __restrict__ E, float* __restrict__ norms) {
    const int k = blockIdx.x * 256 + threadIdx.x;
    float s = 0.f;
    for (int d = 0; d < Ddim; ++d) {
        const float v = E[(size_t)d * Kcode + k];
        s = fmaf(v, v, s);
    }
    norms[k] = s;
}

// ---- fused distance GEMM + argmin + gather + loss partial ----
__global__ __launch_bounds__(256)
void vq_main(const float* __restrict__ X, const float* __restrict__ E,
             const float* __restrict__ ET, const float* __restrict__ norms,
             float* __restrict__ out, float* __restrict__ partials) {
    __shared__ float As[BK][BM];       // transposed inputs tile
    __shared__ float Bs[BK][BN];       // embeddings tile (native layout)
    __shared__ float rv[BM][16];
    __shared__ int   ri[BM][16];
    __shared__ int   rowIdx[BM];
    __shared__ float redbuf[4];

    const int tid = threadIdx.x;
    const int tx = tid % 16, ty = tid / 16;
    const int row0 = blockIdx.x * BM;

    float best[TM];
    int   bidx[TM];
    #pragma unroll
    for (int r = 0; r < TM; ++r) { best[r] = 3.4e38f; bidx[r] = 0; }

    // staging assignments
    const int arow  = tid >> 1;          // 0..127
    const int acol  = (tid & 1) * 16;    // 0 / 16
    const int bkrow = tid >> 3;          // 0..31
    const int bncol = (tid & 7) * 16;    // 0..112

    for (int nc = 0; nc < Kcode / BN; ++nc) {
        const int n0 = nc * BN;
        float acc[TM][TN];
        #pragma unroll
        for (int r = 0; r < TM; ++r)
            #pragma unroll
            for (int c = 0; c < TN; ++c) acc[r][c] = 0.f;

        for (int kd = 0; kd < Ddim / BK; ++kd) {
            // load to regs first (overlaps with waiting on previous compute)
            const float* xp = X + (size_t)(row0 + arow) * Ddim + kd * BK + acol;
            float4 av[4];
            #pragma unroll
            for (int i = 0; i < 4; ++i) av[i] = ((const float4*)xp)[i];
            const float* ep = E + (size_t)(kd * BK + bkrow) * Kcode + n0 + bncol;
            float4 bv[4];
            #pragma unroll
            for (int i = 0; i < 4; ++i) bv[i] = ((const float4*)ep)[i];

            __syncthreads();   // previous tile fully consumed
            #pragma unroll
            for (int i = 0; i < 4; ++i) {
                As[acol + i * 4 + 0][arow] = av[i].x;
                As[acol + i * 4 + 1][arow] = av[i].y;
                As[acol + i * 4 + 2][arow] = av[i].z;
                As[acol + i * 4 + 3][arow] = av[i].w;
                *((float4*)&Bs[bkrow][bncol + i * 4]) = bv[i];
            }
            __syncthreads();

            #pragma unroll 8
            for (int k = 0; k < BK; ++k) {
                float a[TM], b[TN];
                *(float4*)&a[0] = *(const float4*)&As[k][ty * TM];
                *(float4*)&a[4] = *(const float4*)&As[k][ty * TM + 4];
                *(float4*)&b[0] = *(const float4*)&Bs[k][tx * TN];
                *(float4*)&b[4] = *(const float4*)&Bs[k][tx * TN + 4];
                #pragma unroll
                for (int r = 0; r < TM; ++r)
                    #pragma unroll
                    for (int c = 0; c < TN; ++c)
                        acc[r][c] = fmaf(a[r], b[c], acc[r][c]);
            }
        }

        // score + running argmin (codes visited in increasing order per thread)
        #pragma unroll
        for (int c = 0; c < TN; ++c) {
            const int code = n0 + tx * TN + c;
            const float nk = norms[code];
            #pragma unroll
            for (int r = 0; r < TM; ++r) {
                const float s = fmaf(-2.f, acc[r][c], nk);
                if (s < best[r]) { best[r] = s; bidx[r] = code; }
            }
        }
    }

    // cross-thread (tx) argmin reduction per row, lowest-index tie-break
    #pragma unroll
    for (int r = 0; r < TM; ++r) {
        rv[ty * TM + r][tx] = best[r];
        ri[ty * TM + r][tx] = bidx[r];
    }
    __syncthreads();
    if (tid < BM) {
        float bv_ = rv[tid][0];
        int   bi_ = ri[tid][0];
        #pragma unroll
        for (int j = 1; j < 16; ++j) {
            const float v = rv[tid][j];
            const int   i2 = ri[tid][j];
            if (v < bv_ || (v == bv_ && i2 < bi_)) { bv_ = v; bi_ = i2; }
        }
        rowIdx[tid] = bi_;
    }
    __syncthreads();

    // gather + write quantized + loss partial
    const int lane = tid & 63;
    const int grp  = tid >> 6;
    float lsum = 0.f;
    for (int rr = grp; rr < BM; rr += 4) {
        const int row  = row0 + rr;
        const int code = rowIdx[rr];
        float4 q;
        if (ET) {
            q = ((const float4*)(ET + (size_t)code * Ddim))[lane];
        } else {
            const float* ec = E + code;
            q.x = ec[(size_t)(lane * 4 + 0) * Kcode];
            q.y = ec[(size_t)(lane * 4 + 1) * Kcode];
            q.z = ec[(size_t)(lane * 4 + 2) * Kcode];
            q.w = ec[(size_t)(lane * 4 + 3) * Kcode];
        }
        const float4 x = ((const float4*)(X + (size_t)row * Ddim))[lane];
        ((float4*)(out + (size_t)row * Ddim))[lane] = q;
        const float dx = q.x - x.x, dy = q.y - x.y;
        const float dz = q.z - x.z, dw = q.w - x.w;
        lsum += dx * dx + dy * dy + dz * dz + dw * dw;
    }
    #pragma unroll
    for (int off = 32; off > 0; off >>= 1) lsum += __shfl_down(lsum, off, 64);
    if (lane == 0) redbuf[grp] = lsum;
    __syncthreads();
    if (tid == 0)
        partials[blockIdx.x] = redbuf[0] + redbuf[1] + redbuf[2] + redbuf[3];
}

// ---- final loss reduction (deterministic, no atomics) ----
__global__ __launch_bounds__(256)
void vq_loss(const float* __restrict__ partials, float* __restrict__ lossOut) {
    __shared__ float red[4];
    float v = partials[threadIdx.x];
    #pragma unroll
    for (int off = 32; off > 0; off >>= 1) v += __shfl_down(v, off, 64);
    const int lane = threadIdx.x & 63, grp = threadIdx.x >> 6;
    if (lane == 0) red[grp] = v;
    __syncthreads();
    if (threadIdx.x == 0)
        lossOut[0] = 1.25f * (red[0] + red[1] + red[2] + red[3]) /
                     (float)(Mrows * Ddim);
}

extern "C" void kernel_launch(void* const* d_in, const int* in_sizes, int n_in,
                              void* d_out, int out_size, void* d_ws, size_t ws_size,
                              hipStream_t stream) {
    const float* X = (const float*)d_in[0];   // [32768][256]
    const float* E = (const float*)d_in[1];   // [256][1024]
    float* out = (float*)d_out;
    float* ws  = (float*)d_ws;

    const size_t etFloats = (size_t)Kcode * Ddim;  // 262144
    const bool useET = ws_size >= (etFloats + Kcode + 512) * sizeof(float);
    float* ET       = useET ? ws : nullptr;
    float* norms    = useET ? ws + etFloats : ws;
    float* partials = norms + Kcode;

    if (useET)
        vq_prep_transpose<<<256, 256, 0, stream>>>(E, ET);
    vq_norms<<<Kcode / 256, 256, 0, stream>>>(E, norms);
    vq_main<<<Mrows / BM, 256, 0, stream>>>(X, E, ET, norms, out, partials);
    vq_loss<<<1, 256, 0, stream>>>(partials, out + (size_t)Mrows * Ddim);
}

// Round 2
// 280.140 us; speedup vs baseline: 1.2134x; 1.2134x over previous
//
#include <hip/hip_runtime.h>

// ---------------------------------------------------------------------------
// VectorQuantizer: inputs [32,32,32,256] f32, embeddings [256,1024] f32.
// Out: quantized [32768,256] f32 (gathered nearest codebook column),
//      loss scalar = 1.25 * mean((q - x)^2).
// Score: s_k = |e_k|^2 - 2 x.e_k  (|x|^2 is row-constant, dropped).
// R2: 4-way code-split for occupancy (1 -> 4 blocks/CU), bank-conflict-free
//     Bs staging/reads, LDS overlay for the argmin reduction.
// ---------------------------------------------------------------------------

constexpr int Mrows = 32768;
constexpr int Ddim  = 256;
constexpr int Kcode = 1024;

constexpr int BM = 128, BN = 128, BK = 32;
constexpr int TM = 8,  TN = 8;

typedef unsigned long long u64;

__device__ inline u64 packKey(float v, int idx) {
    unsigned u = __float_as_uint(v);
    u = (u & 0x80000000u) ? ~u : (u | 0x80000000u);   // order-preserving
    return ((u64)u << 32) | (unsigned)idx;            // min => (min val, min idx)
}

// ---- codebook transpose: E [D][K] -> ET [K][D] ----
__global__ __launch_bounds__(256)
void vq_prep_transpose(const float* __restrict__ E, float* __restrict__ ET) {
    __shared__ float t[32][33];
    const int k0 = (blockIdx.x % 32) * 32;
    const int d0 = (blockIdx.x / 32) * 32;
    const int tx = threadIdx.x % 32;
    const int ty = threadIdx.x / 32;
    #pragma unroll
    for (int i = 0; i < 32; i += 8)
        t[ty + i][tx] = E[(size_t)(d0 + ty + i) * Kcode + k0 + tx];
    __syncthreads();
    #pragma unroll
    for (int i = 0; i < 32; i += 8)
        ET[(size_t)(k0 + ty + i) * Ddim + d0 + tx] = t[tx][ty + i];
}

// ---- per-code squared norms ----
__global__ __launch_bounds__(256)
void vq_norms(const float* __restrict__ E, float* __restrict__ norms) {
    const int k = blockIdx.x * 256 + threadIdx.x;
    float s = 0.f;
    for (int d = 0; d < Ddim; ++d) {
        const float v = E[(size_t)d * Kcode + k];
        s = fmaf(v, v, s);
    }
    norms[k] = s;
}

// ---- distance GEMM + per-row argmin over this block's code range ----
__global__ __launch_bounds__(256, 4)
void vq_main(const float* __restrict__ X, const float* __restrict__ E,
             const float* __restrict__ norms, u64* __restrict__ keys,
             int codesPerSplit) {
    __shared__ __align__(16) char smemraw[32768];
    float (*As)[BM] = reinterpret_cast<float (*)[BM]>(smemraw);
    float (*Bs)[BN] = reinterpret_cast<float (*)[BN]>(smemraw + BK * BM * 4);

    const int tid = threadIdx.x;
    const int tx = tid % 16, ty = tid / 16;
    const int row0  = blockIdx.x * BM;
    const int split = blockIdx.y;
    const int code0 = split * codesPerSplit;

    float best[TM];
    int   bidx[TM];
    #pragma unroll
    for (int r = 0; r < TM; ++r) { best[r] = 3.4e38f; bidx[r] = 0; }

    // staging: A transposed via scalar writes (2-way, free); B contiguous rows
    const int arow = tid >> 1;           // 0..127
    const int acol = (tid & 1) * 16;     // 0 / 16
    const int bk   = tid >> 5;           // 0..7  (row within BK, step 8)
    const int bn   = (tid & 31) * 4;     // 0..124 (lane-consecutive)

    for (int nc = 0; nc < codesPerSplit / BN; ++nc) {
        const int n0 = code0 + nc * BN;
        float acc[TM][TN];
        #pragma unroll
        for (int r = 0; r < TM; ++r)
            #pragma unroll
            for (int c = 0; c < TN; ++c) acc[r][c] = 0.f;

        for (int kd = 0; kd < Ddim / BK; ++kd) {
            const float* xp = X + (size_t)(row0 + arow) * Ddim + kd * BK + acol;
            float4 av[4];
            #pragma unroll
            for (int i = 0; i < 4; ++i) av[i] = ((const float4*)xp)[i];
            float4 bv[4];
            #pragma unroll
            for (int i = 0; i < 4; ++i)
                bv[i] = *(const float4*)&E[(size_t)(kd * BK + bk + i * 8) * Kcode + n0 + bn];

            __syncthreads();
            #pragma unroll
            for (int i = 0; i < 4; ++i) {
                As[acol + i * 4 + 0][arow] = av[i].x;
                As[acol + i * 4 + 1][arow] = av[i].y;
                As[acol + i * 4 + 2][arow] = av[i].z;
                As[acol + i * 4 + 3][arow] = av[i].w;
                *(float4*)&Bs[bk + i * 8][bn] = bv[i];
            }
            __syncthreads();

            #pragma unroll 8
            for (int k = 0; k < BK; ++k) {
                float a[TM], b[TN];
                *(float4*)&a[0] = *(const float4*)&As[k][ty * TM];
                *(float4*)&a[4] = *(const float4*)&As[k][ty * TM + 4];
                // split-half read: tx*4 stride -> 2-way (free)
                *(float4*)&b[0] = *(const float4*)&Bs[k][tx * 4];
                *(float4*)&b[4] = *(const float4*)&Bs[k][64 + tx * 4];
                #pragma unroll
                for (int r = 0; r < TM; ++r)
                    #pragma unroll
                    for (int c = 0; c < TN; ++c)
                        acc[r][c] = fmaf(a[r], b[c], acc[r][c]);
            }
        }

        // score + running argmin (first-min tie-break by index)
        #pragma unroll
        for (int c = 0; c < TN; ++c) {
            const int col  = (c < 4) ? (tx * 4 + c) : (64 + tx * 4 + (c - 4));
            const int code = n0 + col;
            const float nk = norms[code];
            #pragma unroll
            for (int r = 0; r < TM; ++r) {
                const float s = fmaf(-2.f, acc[r][c], nk);
                if (s < best[r] || (s == best[r] && code < bidx[r])) {
                    best[r] = s; bidx[r] = code;
                }
            }
        }
    }

    // cross-thread reduce via LDS overlay (padded to kill bank conflicts)
    __syncthreads();
    u64* red = reinterpret_cast<u64*>(smemraw);   // [BM][17] fits in 32KB
    #pragma unroll
    for (int r = 0; r < TM; ++r)
        red[(size_t)(ty * TM + r) * 17 + tx] = packKey(best[r], bidx[r]);
    __syncthreads();
    if (tid < BM) {
        u64 m = red[(size_t)tid * 17];
        #pragma unroll
        for (int j = 1; j < 16; ++j) {
            const u64 k2 = red[(size_t)tid * 17 + j];
            m = (k2 < m) ? k2 : m;
        }
        keys[(size_t)split * Mrows + row0 + tid] = m;
    }
}

// ---- merge splits + gather + write quantized + loss partial ----
__global__ __launch_bounds__(256)
void vq_merge(const float* __restrict__ X, const float* __restrict__ E,
              const float* __restrict__ ET, const u64* __restrict__ keys,
              int nsplit, float* __restrict__ out, float* __restrict__ partials) {
    __shared__ float redbuf[4];
    const int tid = threadIdx.x;
    const int lane = tid & 63, grp = tid >> 6;
    const int row0 = blockIdx.x * 128;
    float lsum = 0.f;
    for (int rr = grp; rr < 128; rr += 4) {
        const int row = row0 + rr;
        u64 m = keys[row];
        for (int s2 = 1; s2 < nsplit; ++s2) {
            const u64 k2 = keys[(size_t)s2 * Mrows + row];
            m = (k2 < m) ? k2 : m;
        }
        const int code = (int)(m & 0xFFFFFFFFu);
        float4 q;
        if (ET) {
            q = ((const float4*)(ET + (size_t)code * Ddim))[lane];
        } else {
            const float* ec = E + code;
            q.x = ec[(size_t)(lane * 4 + 0) * Kcode];
            q.y = ec[(size_t)(lane * 4 + 1) * Kcode];
            q.z = ec[(size_t)(lane * 4 + 2) * Kcode];
            q.w = ec[(size_t)(lane * 4 + 3) * Kcode];
        }
        const float4 x = ((const float4*)(X + (size_t)row * Ddim))[lane];
        ((float4*)(out + (size_t)row * Ddim))[lane] = q;
        const float dx = q.x - x.x, dy = q.y - x.y;
        const float dz = q.z - x.z, dw = q.w - x.w;
        lsum += dx * dx + dy * dy + dz * dz + dw * dw;
    }
    #pragma unroll
    for (int off = 32; off > 0; off >>= 1) lsum += __shfl_down(lsum, off, 64);
    if (lane == 0) redbuf[grp] = lsum;
    __syncthreads();
    if (tid == 0)
        partials[blockIdx.x] = redbuf[0] + redbuf[1] + redbuf[2] + redbuf[3];
}

// ---- final loss reduction ----
__global__ __launch_bounds__(256)
void vq_loss(const float* __restrict__ partials, float* __restrict__ lossOut) {
    __shared__ float red[4];
    float v = partials[threadIdx.x];
    #pragma unroll
    for (int off = 32; off > 0; off >>= 1) v += __shfl_down(v, off, 64);
    const int lane = threadIdx.x & 63, grp = threadIdx.x >> 6;
    if (lane == 0) red[grp] = v;
    __syncthreads();
    if (threadIdx.x == 0)
        lossOut[0] = 1.25f * (red[0] + red[1] + red[2] + red[3]) /
                     (float)(Mrows * Ddim);
}

extern "C" void kernel_launch(void* const* d_in, const int* in_sizes, int n_in,
                              void* d_out, int out_size, void* d_ws, size_t ws_size,
                              hipStream_t stream) {
    const float* X = (const float*)d_in[0];
    const float* E = (const float*)d_in[1];
    float* out = (float*)d_out;
    char* ws = (char*)d_ws;

    const size_t etB    = (size_t)Kcode * Ddim * 4;   // 1 MB
    const size_t normsB = (size_t)Kcode * 4;
    const size_t partB  = 256 * 4;

    int nsplit = 4;
    size_t keysB = (size_t)nsplit * Mrows * 8;
    bool useET = true;
    if (ws_size < keysB + etB + normsB + partB) {
        useET = false;
        if (ws_size < keysB + normsB + partB) {
            nsplit = 1;
            keysB = (size_t)Mrows * 8;
            useET = (ws_size >= keysB + etB + normsB + partB);
        }
    }

    u64*   keys     = (u64*)ws;                                   // 8-aligned base
    float* ET       = useET ? (float*)(ws + keysB) : nullptr;
    float* norms    = (float*)(ws + keysB + (useET ? etB : 0));
    float* partials = norms + Kcode;

    if (useET)
        vq_prep_transpose<<<256, 256, 0, stream>>>(E, ET);
    vq_norms<<<Kcode / 256, 256, 0, stream>>>(E, norms);
    vq_main<<<dim3(Mrows / BM, nsplit), 256, 0, stream>>>(X, E, norms, keys,
                                                          Kcode / nsplit);
    vq_merge<<<Mrows / 128, 256, 0, stream>>>(X, E, ET, keys, nsplit, out, partials);
    vq_loss<<<1, 256, 0, stream>>>(partials, out + (size_t)Mrows * Ddim);
}

// Round 3
// 152.435 us; speedup vs baseline: 2.2300x; 1.8378x over previous
//
#include <hip/hip_runtime.h>

// ---------------------------------------------------------------------------
// VectorQuantizer, R3: bf16-MFMA approximate scoring + margin-screened exact
// fp32 rescore. Provably equal argmin to the fp32 path (margin 0.25 >> 2B
// error bound ~0.14 worst case for this data).
// ---------------------------------------------------------------------------

constexpr int Mrows = 32768;
constexpr int Ddim  = 256;
constexpr int Kcode = 1024;

constexpr int   CAP    = 6;
constexpr float MARGIN = 0.25f;

typedef unsigned long long u64;
typedef unsigned short ushort_t;
typedef __attribute__((ext_vector_type(8))) short bf16x8;
typedef __attribute__((ext_vector_type(4))) float f32x4;

__device__ inline u64 packKey(float v, int idx) {
    unsigned u = __float_as_uint(v);
    u = (u & 0x80000000u) ? ~u : (u | 0x80000000u);
    return ((u64)u << 32) | (unsigned)idx;
}
__device__ inline float unpackScore(u64 k) {
    unsigned v = (unsigned)(k >> 32);
    unsigned orig = (v & 0x80000000u) ? (v ^ 0x80000000u) : ~v;
    return __uint_as_float(orig);
}
__device__ inline ushort_t f2bf(float f) {   // RTN-even
    unsigned u = __float_as_uint(f);
    return (ushort_t)((u + 0x7fffu + ((u >> 16) & 1u)) >> 16);
}

// ---- prep: E [D][K] -> ET [K][D] fp32 (+ ETbf bf16) ----
__global__ __launch_bounds__(256)
void vq_prep_transpose(const float* __restrict__ E, float* __restrict__ ET,
                       ushort_t* __restrict__ ETbf) {
    __shared__ float t[32][33];
    const int k0 = (blockIdx.x % 32) * 32;
    const int d0 = (blockIdx.x / 32) * 32;
    const int tx = threadIdx.x % 32;
    const int ty = threadIdx.x / 32;
    #pragma unroll
    for (int i = 0; i < 32; i += 8)
        t[ty + i][tx] = E[(size_t)(d0 + ty + i) * Kcode + k0 + tx];
    __syncthreads();
    #pragma unroll
    for (int i = 0; i < 32; i += 8) {
        const float v = t[tx][ty + i];
        const size_t o = (size_t)(k0 + ty + i) * Ddim + d0 + tx;
        ET[o] = v;
        if (ETbf) ETbf[o] = f2bf(v);
    }
}

// ---- per-code squared norms (exact fp32) ----
__global__ __launch_bounds__(256)
void vq_norms(const float* __restrict__ E, float* __restrict__ norms) {
    const int k = blockIdx.x * 256 + threadIdx.x;
    float s = 0.f;
    for (int d = 0; d < Ddim; ++d) {
        const float v = E[(size_t)d * Kcode + k];
        s = fmaf(v, v, s);
    }
    norms[k] = s;
}

// ---- MFMA scoring: 128 rows x 128 codes per block, candidates via margin ----
__global__ __launch_bounds__(256, 2)
void vq_score(const float* __restrict__ X, const ushort_t* __restrict__ Ebf,
              const float* __restrict__ norms, u64* __restrict__ minkeys,
              u64* __restrict__ cands, int* __restrict__ counts) {
    __shared__ __align__(16) char sm[32768];   // A tile 16KB | B tile 16KB
    __shared__ u64 rowmin[128];
    __shared__ u64 rowcand[128][CAP];
    __shared__ int rowcnt[128];

    char* smA = sm;
    char* smB = sm + 16384;

    const int tid = threadIdx.x;
    const int l = tid & 63;
    const int w = tid >> 6;           // wave 0..3
    const int wr = w >> 1, wc = w & 1;
    const int n0   = blockIdx.x * 128;   // code block (8)
    const int row0 = blockIdx.y * 128;   // row block (256)

    if (tid < 128) { rowmin[tid] = ~0ULL; rowcnt[tid] = 0; }

    f32x4 acc[4][4];
    #pragma unroll
    for (int i = 0; i < 4; ++i)
        #pragma unroll
        for (int j = 0; j < 4; ++j) acc[i][j] = {0.f, 0.f, 0.f, 0.f};

    for (int kd = 0; kd < 4; ++kd) {          // BK = 64
        // ---- reg-stage loads (issue before barrier) ----
        float4 av[4][2];
        uint4  bv[4];
        #pragma unroll
        for (int j = 0; j < 4; ++j) {
            const int chunk = j * 256 + tid;       // 1024 x 16B bf16 chunks
            const int row = chunk >> 3, slot = chunk & 7;
            const float* xp = X + (size_t)(row0 + row) * Ddim + kd * 64 + slot * 8;
            av[j][0] = *(const float4*)xp;
            av[j][1] = *(const float4*)(xp + 4);
            bv[j] = *(const uint4*)(Ebf + (size_t)(n0 + row) * Ddim + kd * 64 + slot * 8);
        }
        __syncthreads();   // previous tile fully consumed
        #pragma unroll
        for (int j = 0; j < 4; ++j) {
            const int chunk = j * 256 + tid;
            const int row = chunk >> 3, slot = chunk & 7;
            union { uint4 v; ushort_t u[8]; } cv;
            cv.u[0] = f2bf(av[j][0].x); cv.u[1] = f2bf(av[j][0].y);
            cv.u[2] = f2bf(av[j][0].z); cv.u[3] = f2bf(av[j][0].w);
            cv.u[4] = f2bf(av[j][1].x); cv.u[5] = f2bf(av[j][1].y);
            cv.u[6] = f2bf(av[j][1].z); cv.u[7] = f2bf(av[j][1].w);
            *(uint4*)(smA + row * 128 + ((slot * 16) ^ ((row & 7) << 4))) = cv.v;
            *(uint4*)(smB + row * 128 + ((slot * 16) ^ ((row & 7) << 4))) = bv[j];
        }
        __syncthreads();

        #pragma unroll
        for (int kk = 0; kk < 2; ++kk) {      // two 16x16x32 steps per BK=64
            const int kbyte = kk * 64 + (l >> 4) * 16;
            bf16x8 a[4], b[4];
            #pragma unroll
            for (int f = 0; f < 4; ++f) {
                const int ra = wr * 64 + f * 16 + (l & 15);
                const int rb = wc * 64 + f * 16 + (l & 15);
                a[f] = *(const bf16x8*)(smA + ra * 128 + (kbyte ^ ((ra & 7) << 4)));
                b[f] = *(const bf16x8*)(smB + rb * 128 + (kbyte ^ ((rb & 7) << 4)));
            }
            #pragma unroll
            for (int fm = 0; fm < 4; ++fm)
                #pragma unroll
                for (int fn = 0; fn < 4; ++fn)
                    acc[fm][fn] = __builtin_amdgcn_mfma_f32_16x16x32_bf16(
                        a[fm], b[fn], acc[fm][fn], 0, 0, 0);
        }
    }

    // ---- epilogue: scores, block-local argmin, candidate collection ----
    float nk[4]; int colv[4];
    #pragma unroll
    for (int fn = 0; fn < 4; ++fn) {
        colv[fn] = n0 + wc * 64 + fn * 16 + (l & 15);
        nk[fn] = norms[colv[fn]];
    }

    // pass 1: per-row min (16-lane shuffle reduce + LDS atomicMin)
    #pragma unroll
    for (int fm = 0; fm < 4; ++fm)
        #pragma unroll
        for (int r = 0; r < 4; ++r) {
            u64 key = ~0ULL;
            #pragma unroll
            for (int fn = 0; fn < 4; ++fn) {
                const float s = fmaf(-2.f, acc[fm][fn][r], nk[fn]);
                const u64 k2 = packKey(s, colv[fn]);
                if (k2 < key) key = k2;
            }
            #pragma unroll
            for (int off = 1; off < 16; off <<= 1) {
                const u64 o = __shfl_xor(key, off, 16);
                if (o < key) key = o;
            }
            if ((l & 15) == 0)
                atomicMin(&rowmin[wr * 64 + fm * 16 + (l >> 4) * 4 + r], key);
        }
    __syncthreads();

    // pass 2: collect codes within margin of row-local min
    #pragma unroll
    for (int fm = 0; fm < 4; ++fm)
        #pragma unroll
        for (int r = 0; r < 4; ++r) {
            const int rl = wr * 64 + fm * 16 + (l >> 4) * 4 + r;
            const float thr = unpackScore(rowmin[rl]) + MARGIN;
            #pragma unroll
            for (int fn = 0; fn < 4; ++fn) {
                const float s = fmaf(-2.f, acc[fm][fn][r], nk[fn]);
                if (s <= thr) {
                    const int p = atomicAdd(&rowcnt[rl], 1);
                    if (p < CAP) rowcand[rl][p] = packKey(s, colv[fn]);
                }
            }
        }
    __syncthreads();

    // ---- write block results ----
    const int bc = blockIdx.x;
    if (tid < 128) {
        minkeys[(size_t)bc * Mrows + row0 + tid] = rowmin[tid];
        counts [(size_t)bc * Mrows + row0 + tid] = rowcnt[tid];
    }
    for (int e = tid; e < 128 * CAP; e += 256) {
        const int r = e / CAP, c = e % CAP;
        const int cnt = rowcnt[r] < CAP ? rowcnt[r] : CAP;
        cands[((size_t)bc * Mrows + row0 + r) * CAP + c] =
            (c < cnt) ? rowcand[r][c] : ~0ULL;
    }
}

// ---- merge: exact fp32 rescore of candidates + gather + loss ----
__global__ __launch_bounds__(256)
void vq_merge_mfma(const float* __restrict__ X, const float* __restrict__ ET,
                   const float* __restrict__ norms,
                   const u64* __restrict__ minkeys, const int* __restrict__ counts,
                   const u64* __restrict__ cands,
                   float* __restrict__ out, double* __restrict__ partials) {
    __shared__ double redbuf[4];
    const int tid = threadIdx.x;
    const int lane = tid & 63, w = tid >> 6;
    double lsum = 0.0;

    for (int rr = 0; rr < 4; ++rr) {
        const int row = blockIdx.x * 16 + w * 4 + rr;
        const float4 x4 = ((const float4*)(X + (size_t)row * Ddim))[lane];

        // global approx min over the 8 block minima
        u64 k = ~0ULL;
        if (lane < 8) k = minkeys[(size_t)lane * Mrows + row];
        #pragma unroll
        for (int off = 4; off; off >>= 1) {
            const u64 o = __shfl_xor(k, off, 8);
            if (o < k) k = o;
        }
        k = __shfl(k, 0, 64);
        const float gthr = unpackScore(k) + MARGIN;

        float bestS = 3.4e38f; int bestI = 0x7fffffff;
        auto rescore = [&](int code) {
            const float4 e4 = ((const float4*)(ET + (size_t)code * Ddim))[lane];
            float d = x4.x * e4.x;
            d = fmaf(x4.y, e4.y, d);
            d = fmaf(x4.z, e4.z, d);
            d = fmaf(x4.w, e4.w, d);
            #pragma unroll
            for (int off = 32; off; off >>= 1) d += __shfl_xor(d, off, 64);
            const float s = norms[code] - 2.f * d;
            if (s < bestS || (s == bestS && code < bestI)) { bestS = s; bestI = code; }
        };

        for (int b = 0; b < 8; ++b) {
            const int cnt = counts[(size_t)b * Mrows + row];
            if (cnt <= CAP) {
                u64 ck = ~0ULL;
                if (lane < CAP && lane < cnt)
                    ck = cands[((size_t)b * Mrows + row) * CAP + lane];
                const bool ok = (ck != ~0ULL) && (unpackScore(ck) <= gthr);
                u64 mask = __ballot(ok);
                while (mask) {
                    const int src = __ffsll((unsigned long long)mask) - 1;
                    mask &= mask - 1;
                    const int code = (int)(__shfl(ck, src, 64) & 0xffffffffu);
                    rescore(code);
                }
            } else {  // overflow (statistically never): exact rescan of block
                if (unpackScore(minkeys[(size_t)b * Mrows + row]) <= gthr)
                    for (int code = b * 128; code < b * 128 + 128; ++code)
                        rescore(code);
            }
        }

        // gather + write + loss
        const float4 q4 = ((const float4*)(ET + (size_t)bestI * Ddim))[lane];
        ((float4*)(out + (size_t)row * Ddim))[lane] = q4;
        const double dx = (double)(q4.x - x4.x), dy = (double)(q4.y - x4.y);
        const double dz = (double)(q4.z - x4.z), dw = (double)(q4.w - x4.w);
        lsum += dx * dx + dy * dy + dz * dz + dw * dw;
    }
    #pragma unroll
    for (int off = 32; off; off >>= 1) lsum += __shfl_down(lsum, off, 64);
    if (lane == 0) redbuf[w] = lsum;
    __syncthreads();
    if (tid == 0)
        partials[blockIdx.x] = redbuf[0] + redbuf[1] + redbuf[2] + redbuf[3];
}

__global__ __launch_bounds__(256)
void vq_loss_mfma(const double* __restrict__ partials, float* __restrict__ lossOut) {
    __shared__ double red[4];
    double v = 0.0;
    for (int i = threadIdx.x; i < 2048; i += 256) v += partials[i];
    #pragma unroll
    for (int off = 32; off; off >>= 1) v += __shfl_down(v, off, 64);
    const int lane = threadIdx.x & 63, grp = threadIdx.x >> 6;
    if (lane == 0) red[grp] = v;
    __syncthreads();
    if (threadIdx.x == 0)
        lossOut[0] = (float)(1.25 * (red[0] + red[1] + red[2] + red[3]) /
                             (double)((size_t)Mrows * Ddim));
}

// ===================== R2 fp32 fallback path (proven) ======================
__global__ __launch_bounds__(256, 4)
void vq_main_f32(const float* __restrict__ X, const float* __restrict__ E,
                 const float* __restrict__ norms, u64* __restrict__ keys,
                 int codesPerSplit) {
    constexpr int BM = 128, BN = 128, BK = 32, TM = 8, TN = 8;
    __shared__ __align__(16) char smemraw[32768];
    float (*As)[BM] = reinterpret_cast<float (*)[BM]>(smemraw);
    float (*Bs)[BN] = reinterpret_cast<float (*)[BN]>(smemraw + BK * BM * 4);
    const int tid = threadIdx.x;
    const int tx = tid % 16, ty = tid / 16;
    const int row0 = blockIdx.x * BM;
    const int split = blockIdx.y;
    const int code0 = split * codesPerSplit;
    float best[TM]; int bidx[TM];
    #pragma unroll
    for (int r = 0; r < TM; ++r) { best[r] = 3.4e38f; bidx[r] = 0; }
    const int arow = tid >> 1, acol = (tid & 1) * 16;
    const int bk = tid >> 5, bn = (tid & 31) * 4;
    for (int nc = 0; nc < codesPerSplit / BN; ++nc) {
        const int n0 = code0 + nc * BN;
        float acc[TM][TN];
        #pragma unroll
        for (int r = 0; r < TM; ++r)
            #pragma unroll
            for (int c = 0; c < TN; ++c) acc[r][c] = 0.f;
        for (int kd = 0; kd < Ddim / BK; ++kd) {
            const float* xp = X + (size_t)(row0 + arow) * Ddim + kd * BK + acol;
            float4 av[4];
            #pragma unroll
            for (int i = 0; i < 4; ++i) av[i] = ((const float4*)xp)[i];
            float4 bv[4];
            #pragma unroll
            for (int i = 0; i < 4; ++i)
                bv[i] = *(const float4*)&E[(size_t)(kd * BK + bk + i * 8) * Kcode + n0 + bn];
            __syncthreads();
            #pragma unroll
            for (int i = 0; i < 4; ++i) {
                As[acol + i * 4 + 0][arow] = av[i].x;
                As[acol + i * 4 + 1][arow] = av[i].y;
                As[acol + i * 4 + 2][arow] = av[i].z;
                As[acol + i * 4 + 3][arow] = av[i].w;
                *(float4*)&Bs[bk + i * 8][bn] = bv[i];
            }
            __syncthreads();
            #pragma unroll 8
            for (int k = 0; k < BK; ++k) {
                float a[TM], b[TN];
                *(float4*)&a[0] = *(const float4*)&As[k][ty * TM];
                *(float4*)&a[4] = *(const float4*)&As[k][ty * TM + 4];
                *(float4*)&b[0] = *(const float4*)&Bs[k][tx * 4];
                *(float4*)&b[4] = *(const float4*)&Bs[k][64 + tx * 4];
                #pragma unroll
                for (int r = 0; r < TM; ++r)
                    #pragma unroll
                    for (int c = 0; c < TN; ++c)
                        acc[r][c] = fmaf(a[r], b[c], acc[r][c]);
            }
        }
        #pragma unroll
        for (int c = 0; c < TN; ++c) {
            const int col = (c < 4) ? (tx * 4 + c) : (64 + tx * 4 + (c - 4));
            const int code = n0 + col;
            const float nkv = norms[code];
            #pragma unroll
            for (int r = 0; r < TM; ++r) {
                const float s = fmaf(-2.f, acc[r][c], nkv);
                if (s < best[r] || (s == best[r] && code < bidx[r])) {
                    best[r] = s; bidx[r] = code;
                }
            }
        }
    }
    __syncthreads();
    u64* red = reinterpret_cast<u64*>(smemraw);
    #pragma unroll
    for (int r = 0; r < TM; ++r)
        red[(size_t)(ty * TM + r) * 17 + tx] = packKey(best[r], bidx[r]);
    __syncthreads();
    if (tid < BM) {
        u64 m = red[(size_t)tid * 17];
        #pragma unroll
        for (int j = 1; j < 16; ++j) {
            const u64 k2 = red[(size_t)tid * 17 + j];
            m = (k2 < m) ? k2 : m;
        }
        keys[(size_t)split * Mrows + row0 + tid] = m;
    }
}

__global__ __launch_bounds__(256)
void vq_merge_f32(const float* __restrict__ X, const float* __restrict__ E,
                  const float* __restrict__ ET, const u64* __restrict__ keys,
                  int nsplit, float* __restrict__ out, float* __restrict__ partials) {
    __shared__ float redbuf[4];
    const int tid = threadIdx.x;
    const int lane = tid & 63, grp = tid >> 6;
    const int row0 = blockIdx.x * 128;
    float lsum = 0.f;
    for (int rr = grp; rr < 128; rr += 4) {
        const int row = row0 + rr;
        u64 m = keys[row];
        for (int s2 = 1; s2 < nsplit; ++s2) {
            const u64 k2 = keys[(size_t)s2 * Mrows + row];
            m = (k2 < m) ? k2 : m;
        }
        const int code = (int)(m & 0xFFFFFFFFu);
        float4 q;
        if (ET) {
            q = ((const float4*)(ET + (size_t)code * Ddim))[lane];
        } else {
            const float* ec = E + code;
            q.x = ec[(size_t)(lane * 4 + 0) * Kcode];
            q.y = ec[(size_t)(lane * 4 + 1) * Kcode];
            q.z = ec[(size_t)(lane * 4 + 2) * Kcode];
            q.w = ec[(size_t)(lane * 4 + 3) * Kcode];
        }
        const float4 x = ((const float4*)(X + (size_t)row * Ddim))[lane];
        ((float4*)(out + (size_t)row * Ddim))[lane] = q;
        const float dx = q.x - x.x, dy = q.y - x.y;
        const float dz = q.z - x.z, dw = q.w - x.w;
        lsum += dx * dx + dy * dy + dz * dz + dw * dw;
    }
    #pragma unroll
    for (int off = 32; off > 0; off >>= 1) lsum += __shfl_down(lsum, off, 64);
    if (lane == 0) redbuf[grp] = lsum;
    __syncthreads();
    if (tid == 0)
        partials[blockIdx.x] = redbuf[0] + redbuf[1] + redbuf[2] + redbuf[3];
}

__global__ __launch_bounds__(256)
void vq_loss_f32(const float* __restrict__ partials, float* __restrict__ lossOut) {
    __shared__ float red[4];
    float v = partials[threadIdx.x];
    #pragma unroll
    for (int off = 32; off > 0; off >>= 1) v += __shfl_down(v, off, 64);
    const int lane = threadIdx.x & 63, grp = threadIdx.x >> 6;
    if (lane == 0) red[grp] = v;
    __syncthreads();
    if (threadIdx.x == 0)
        lossOut[0] = 1.25f * (red[0] + red[1] + red[2] + red[3]) /
                     (float)(Mrows * Ddim);
}

// ===========================================================================
extern "C" void kernel_launch(void* const* d_in, const int* in_sizes, int n_in,
                              void* d_out, int out_size, void* d_ws, size_t ws_size,
                              hipStream_t stream) {
    const float* X = (const float*)d_in[0];
    const float* E = (const float*)d_in[1];
    float* out = (float*)d_out;
    char* ws = (char*)d_ws;

    // MFMA-path workspace layout (8-byte types first)
    const size_t minkeysB = (size_t)8 * Mrows * 8;          //  2 MB
    const size_t candsB   = (size_t)8 * Mrows * CAP * 8;    // 12.6 MB
    const size_t partB    = 2048 * 8;                       // 16 KB
    const size_t etB      = (size_t)Kcode * Ddim * 4;       //  1 MB
    const size_t etbfB    = (size_t)Kcode * Ddim * 2;       // 0.5 MB
    const size_t normsB   = (size_t)Kcode * 4;
    const size_t countsB  = (size_t)8 * Mrows * 4;          //  1 MB
    const size_t need = minkeysB + candsB + partB + etB + etbfB + normsB + countsB;

    if (ws_size >= need) {
        char* p = ws;
        u64*      minkeys  = (u64*)p;      p += minkeysB;
        u64*      cands    = (u64*)p;      p += candsB;
        double*   partials = (double*)p;   p += partB;
        float*    ET       = (float*)p;    p += etB;
        ushort_t* ETbf     = (ushort_t*)p; p += etbfB;
        float*    norms    = (float*)p;    p += normsB;
        int*      counts   = (int*)p;

        vq_prep_transpose<<<256, 256, 0, stream>>>(E, ET, ETbf);
        vq_norms<<<Kcode / 256, 256, 0, stream>>>(E, norms);
        vq_score<<<dim3(8, 256), 256, 0, stream>>>(X, ETbf, norms, minkeys, cands, counts);
        vq_merge_mfma<<<Mrows / 16, 256, 0, stream>>>(X, ET, norms, minkeys, counts,
                                                      cands, out, partials);
        vq_loss_mfma<<<1, 256, 0, stream>>>(partials, out + (size_t)Mrows * Ddim);
    } else {
        // R2 fp32 fallback
        int nsplit = 4;
        size_t keysB = (size_t)nsplit * Mrows * 8;
        bool useET = true;
        if (ws_size < keysB + etB + normsB + 1024) {
            useET = false;
            if (ws_size < keysB + normsB + 1024) {
                nsplit = 1;
                keysB = (size_t)Mrows * 8;
                useET = (ws_size >= keysB + etB + normsB + 1024);
            }
        }
        u64*   keys     = (u64*)ws;
        float* ET       = useET ? (float*)(ws + keysB) : nullptr;
        float* norms    = (float*)(ws + keysB + (useET ? etB : 0));
        float* partials = norms + Kcode;

        if (useET)
            vq_prep_transpose<<<256, 256, 0, stream>>>(E, ET, nullptr);
        vq_norms<<<Kcode / 256, 256, 0, stream>>>(E, norms);
        vq_main_f32<<<dim3(Mrows / 128, nsplit), 256, 0, stream>>>(X, E, norms, keys,
                                                                   Kcode / nsplit);
        vq_merge_f32<<<Mrows / 128, 256, 0, stream>>>(X, E, ET, keys, nsplit, out, partials);
        vq_loss_f32<<<1, 256, 0, stream>>>(partials, out + (size_t)Mrows * Ddim);
    }
}